// Round 21
// baseline (127.721 us; speedup 1.0000x reference)
//
#include <hip/hip_runtime.h>

// NavierStokesLoss: fused jet-propagation (8 channels/point) through
// 4->256->256->5 tanh MLP. R21 = R19 (109.9us; best tie with R16) with the
// G3+tail widened to 4 waves x 2 points (one 16x16 MFMA covers both channel
// halves of 2 points via per-lane A-row addressing) -> per-wave tail work
// halves (8 MFMAs + 8 LDS reads vs 16+16). Partner half via shfl_xor(32)
// (R11-validated). red[8] + final barrier (R19 structure; R20's early-exit
// regressed). fp8 MFMA (absmax 0.002), 32x32x16 GEMM2, packed-f32 L1/RC,
// 4-bit XOR swizzle, launch_bounds(512,6).

#define NPTS 65536
#define BP   8
#define NBLK (NPTS / BP)      // 8192
#define KPADB 264             // byte stride of one W2^T row (256 fp8 + 8 pad)
#define W3T_OFF 135168
#define PART_OFF 143360

typedef float f32x2 __attribute__((ext_vector_type(2)));
typedef float f32x4 __attribute__((ext_vector_type(4)));
typedef float f32x16 __attribute__((ext_vector_type(16)));

static __device__ __forceinline__ unsigned cvtpk_fp8(float lo, float hi){
  unsigned r = 0;
  asm("v_cvt_pk_fp8_f32 %0, %1, %2" : "+v"(r) : "v"(lo), "v"(hi));
  return r;   // bytes [0]=fp8(lo), [1]=fp8(hi)
}
static __device__ __forceinline__ float fast_tanh(float x){
  float e = __builtin_amdgcn_exp2f(x * 2.8853900817779268f);   // exp(2x)
  return 1.f - 2.f * __builtin_amdgcn_rcpf(e + 1.f);
}

// W2 (256x256 f32, [k][j]) -> w2t fp8 [j][KPADB] (transposed, padded rows)
__global__ void prep_w2t(const float* __restrict__ W2, unsigned char* __restrict__ w2t){
  int kp = blockIdx.x, j = threadIdx.x;          // 128 k-pairs
  float lo = W2[(2*kp    )*256 + j];
  float hi = W2[(2*kp + 1)*256 + j];
  *(unsigned short*)(w2t + j*KPADB + 2*kp) = (unsigned short)cvtpk_fp8(lo, hi);
}
// W3 (256x5 f32, [k][n]) -> w3t fp8 [16][256] (transposed, rows 5..15 zero)
__global__ void prep_w3t(const float* __restrict__ W3, unsigned char* __restrict__ w3t){
  int n = blockIdx.x, k2 = threadIdx.x * 2;      // 16 x 128
  float lo = (n < 5) ? W3[k2*5 + n]       : 0.f;
  float hi = (n < 5) ? W3[(k2+1)*5 + n]   : 0.f;
  *(unsigned short*)(w3t + n*256 + k2) = (unsigned short)cvtpk_fp8(lo, hi);
}

// Jet-tile row layout (64 rows x 256 fp8, 256B rows, XOR swizzle (row&15)<<3):
//   row(p,c) = (p&4)*8 + (c&4)*4 + (p&3)*4 + (c&3)
__launch_bounds__(512, 6)
__global__ void ns_main(const float* __restrict__ pts, const float* __restrict__ times,
                        const float* __restrict__ visc,
                        const float* __restrict__ W1, const float* __restrict__ b1,
                        const float* __restrict__ b2, const float* __restrict__ b3,
                        const unsigned char* __restrict__ w2t,
                        const unsigned char* __restrict__ w3t,
                        float* __restrict__ parts){
  __shared__ __align__(16) unsigned char sA[64 * 256];   // 16 KiB
  __shared__ float red[8];

  const int t   = threadIdx.x;
  const int blk = blockIdx.x;

  // ---------------- layer 1: seed the jet, write fp8 A-tile (packed f32) ----------------
  {
    int p  = t >> 6;            // 8 points, one wave each
    int jo = (t & 63) << 2;     // 4 consecutive j per thread
    int n  = blk * BP + p;
    float z0 = pts[n*3+0], z1 = pts[n*3+1], z2 = pts[n*3+2], z3 = times[n];
    float4 wa  = *(const float4*)(W1 + jo);
    float4 wb  = *(const float4*)(W1 + 256 + jo);
    float4 wcv = *(const float4*)(W1 + 512 + jo);
    float4 wd  = *(const float4*)(W1 + 768 + jo);
    float4 bb  = *(const float4*)(b1 + jo);
    f32x2 w0p[2] = {{wa.x, wa.y}, {wa.z, wa.w}};
    f32x2 w1p[2] = {{wb.x, wb.y}, {wb.z, wb.w}};
    f32x2 w2p[2] = {{wcv.x, wcv.y}, {wcv.z, wcv.w}};
    f32x2 w3p2[2] = {{wd.x, wd.y}, {wd.z, wd.w}};
    f32x2 bbp[2] = {{bb.x, bb.y}, {bb.z, bb.w}};
    f32x2 th[2], sg[2], m2[2];
    #pragma unroll
    for (int pp = 0; pp < 2; ++pp){
      f32x2 a = bbp[pp] + z0*w0p[pp] + z1*w1p[pp] + z2*w2p[pp] + z3*w3p2[pp];
      th[pp] = (f32x2){fast_tanh(a.x), fast_tanh(a.y)};
      sg[pp] = 1.f - th[pp]*th[pp];
      m2[pp] = -2.f * th[pp] * sg[pp];
    }
    #pragma unroll
    for (int c = 0; c < 8; ++c){
      f32x2 x[2];
      #pragma unroll
      for (int pp = 0; pp < 2; ++pp){
        f32x2 v;
        if      (c == 0) v = th[pp];
        else if (c == 1) v = sg[pp]*w0p[pp];
        else if (c == 2) v = sg[pp]*w1p[pp];
        else if (c == 3) v = sg[pp]*w2p[pp];
        else if (c == 4) v = sg[pp]*w3p2[pp];
        else if (c == 5) v = (m2[pp]*w0p[pp])*w0p[pp];
        else if (c == 6) v = (m2[pp]*w1p[pp])*w1p[pp];
        else             v = (m2[pp]*w2p[pp])*w2p[pp];
        x[pp] = v;
      }
      int row = ((p & 4) << 3) + ((c & 4) << 2) + ((p & 3) << 2) + (c & 3);
      int off = row*256 + (jo ^ ((row & 15) << 3));
      unsigned v32 = cvtpk_fp8(x[0].x, x[0].y) | (cvtpk_fp8(x[1].x, x[1].y) << 16);
      *(unsigned*)(sA + off) = v32;
    }
  }
  __syncthreads();

  const int wid = t >> 6, lane = t & 63;
  const int g = lane >> 4, r16 = lane & 15;
  const int l31 = lane & 31, h = lane >> 5;
  const int rsw2 = (l31 & 15) << 3;  // 32x32-path swizzle

  // ------- GEMM2: A(64x256) @ W2 cols wid*32..+31, 32x32x16 fp8 MFMA -------
  f32x16 acc32[2];
  #pragma unroll
  for (int i = 0; i < 16; ++i){ acc32[0][i] = 0.f; acc32[1][i] = 0.f; }

  {
    const unsigned char* bp2 = w2t + (wid*32 + l31)*KPADB + h*8;
    int abase = l31*256;
    __builtin_amdgcn_s_setprio(1);
    #pragma unroll
    for (int ks = 0; ks < 16; ++ks){
      int k0 = ks * 16;
      int X  = (k0 + (h << 3)) ^ rsw2;
      long a0 = *(const long*)(sA + abase + X);
      long a1 = *(const long*)(sA + abase + 8192 + X);
      long bv = *(const long*)(bp2 + k0);
      acc32[0] = __builtin_amdgcn_mfma_f32_32x32x16_fp8_fp8(a0, bv, acc32[0], 0, 0, 0);
      acc32[1] = __builtin_amdgcn_mfma_f32_32x32x16_fp8_fp8(a1, bv, acc32[1], 0, 0, 0);
    }
    __builtin_amdgcn_s_setprio(0);
  }
  __syncthreads();   // all A-tile reads complete before in-place overwrite

  // ------- recombine (tanh jet through layer-2), packed f32, fp8 writes -------
  // acc32[mt] reg r: C row-in-tile = (r&3) + 8*(r>>2) + 4*h ; col j = wid*32+l31.
  // For rr=r>>2 in {0,1}: pt = mt*4 + 2*rr + h, ch = r&3 (lo); reg r+8 = ch+4 (hi).
  {
    float b2j = b2[wid*32 + l31];
    int colj = wid*32 + l31;
    #pragma unroll
    for (int mt = 0; mt < 2; ++mt){
      #pragma unroll
      for (int rr = 0; rr < 2; ++rr){
        int pt = mt*4 + rr*2 + h;
        float v0 = acc32[mt][rr*4 + 0];
        f32x2 v12 = {acc32[mt][rr*4 + 1], acc32[mt][rr*4 + 2]};
        float v3 = acc32[mt][rr*4 + 3];
        float w0 = acc32[mt][rr*4 + 8];
        f32x2 w12 = {acc32[mt][rr*4 + 9], acc32[mt][rr*4 + 10]};
        float w3 = acc32[mt][rr*4 + 11];
        float gv = fast_tanh(v0 + b2j);
        float s2 = 1.f - gv*gv;
        float t2 = -2.f * gv * s2;
        f32x2 rlo12 = s2 * v12;
        float rlo3  = s2 * v3;
        float rhi0  = s2 * w0;
        f32x2 rhi12 = (t2*v12)*v12 + s2*w12;
        float rhi3  = fmaf(t2*v3, v3, s2*w3);
        int rbase = ((pt & 4) << 3) + ((pt & 3) << 2);
        unsigned u;
        int row0 = rbase, adr0 = row0*256 + (colj ^ ((row0 & 15) << 3));
        u = cvtpk_fp8(gv, rhi0);
        *(unsigned char*)(sA + adr0)        = (unsigned char)u;
        *(unsigned char*)(sA + adr0 + 4096) = (unsigned char)(u >> 8);
        int row1 = rbase + 1, adr1 = row1*256 + (colj ^ ((row1 & 15) << 3));
        u = cvtpk_fp8(rlo12.x, rhi12.x);
        *(unsigned char*)(sA + adr1)        = (unsigned char)u;
        *(unsigned char*)(sA + adr1 + 4096) = (unsigned char)(u >> 8);
        int row2 = rbase + 2, adr2 = row2*256 + (colj ^ ((row2 & 15) << 3));
        u = cvtpk_fp8(rlo12.y, rhi12.y);
        *(unsigned char*)(sA + adr2)        = (unsigned char)u;
        *(unsigned char*)(sA + adr2 + 4096) = (unsigned char)(u >> 8);
        int row3 = rbase + 3, adr3 = row3*256 + (colj ^ ((row3 & 15) << 3));
        u = cvtpk_fp8(rlo3, rhi3);
        *(unsigned char*)(sA + adr3)        = (unsigned char)u;
        *(unsigned char*)(sA + adr3 + 4096) = (unsigned char)(u >> 8);
      }
    }
  }
  __syncthreads();

  // ---- GEMM3 + in-register residual tail: waves 0-3, 2 points each ----
  // Wave w handles points 2w, 2w+1. A tile row i (0-15):
  //   pt = 2w + ((i>>2)&1), half = i>>3, ch = (i&3) + 4*half
  // -> lane r16 loads jet row jrow(r16). C: lane (g, n=r16) holds, for
  // point 2w+(g&1), half g>>1, the 4 channels in a3[0..3]. Partner half
  // via shfl_xor(32). Residual computed on lanes g<2.
  if (wid < 4){
    const unsigned char* w3p = w3t + r16*256 + g*8;
    int ptA  = 2*wid + ((r16 >> 2) & 1);
    int half = r16 >> 3;
    int jrow = ((ptA & 4) << 3) + (half << 4) + ((ptA & 3) << 2) + (r16 & 3);
    int gb   = jrow * 256;
    int jsw  = (jrow & 15) << 3;
    f32x4 a3 = (f32x4){0.f, 0.f, 0.f, 0.f};
    #pragma unroll
    for (int ks = 0; ks < 8; ++ks){
      int k0 = ks * 32;
      int X  = (k0 + (g << 3)) ^ jsw;
      long av  = *(const long*)(sA + gb + X);
      long bv3 = *(const long*)(w3p + k0);
      a3 = __builtin_amdgcn_mfma_f32_16x16x32_fp8_fp8(av, bv3, a3, 0, 0, 0);
    }
    // partner half (lanes g^2 = lane^32)
    float o4 = __shfl_xor(a3[0], 32, 64);
    float o5 = __shfl_xor(a3[1], 32, 64);
    float o6 = __shfl_xor(a3[2], 32, 64);
    float o7 = __shfl_xor(a3[3], 32, 64);
    float b3v = (r16 < 5) ? b3[r16] : 0.f;
    float o0 = a3[0] + b3v;                    // value channel + bias (lanes g<2)
    float o1 = a3[1], o2 = a3[2], o3 = a3[3];
    int sl = lane & 48;                        // own 16-lane group base
    float u0   = __shfl(o0, sl | 0, 64);
    float u1   = __shfl(o0, sl | 1, 64);
    float u2   = __shfl(o0, sl | 2, 64);
    float rhoA = __shfl(o0, sl | 4, 64);
    float gpx  = __shfl(o1, sl | 3, 64);
    float gpy  = __shfl(o2, sl | 3, 64);
    float gpz  = __shfl(o3, sl | 3, 64);
    float c00  = __shfl(o1, sl | 0, 64);
    float c11  = __shfl(o2, sl | 1, 64);
    float c22  = __shfl(o3, sl | 2, 64);
    float rho = 1000.f * (1.f + 0.1f * fast_tanh(rhoA));
    float rr  = __builtin_amdgcn_rcpf(rho);
    float vis = visc[blk*BP + 2*wid + (g & 1)];
    float lap = o5 + o6 + o7;
    float cv  = u0*o1 + u1*o2 + u2*o3;
    float gp  = (r16 == 0) ? gpx : ((r16 == 1) ? gpy : gpz);
    float R   = o4 + cv + gp*rr - vis*lap + ((r16 == 1) ? 9.81f : 0.f);
    float accM = (g < 2 && r16 < 3) ? R*R : 0.f;
    float accC = 0.f;
    if (g < 2 && r16 == 3){ float Rc = c00 + c11 + c22; accC = Rc*Rc; }
    #pragma unroll
    for (int off = 1; off < 64; off <<= 1){
      accM += __shfl_xor(accM, off, 64);
      accC += __shfl_xor(accC, off, 64);
    }
    if (lane == 0){ red[wid*2] = accM; red[wid*2+1] = accC; }
  }
  __syncthreads();
  if (t == 0){
    float2 pr;
    pr.x = red[0] + red[2] + red[4] + red[6];
    pr.y = red[1] + red[3] + red[5] + red[7];
    *(float2*)(parts + blk*2) = pr;
  }
}

__global__ void ns_reduce(const float* __restrict__ parts, float* __restrict__ out){
  int t = threadIdx.x;
  float a = 0.f, b = 0.f;
  for (int i = t; i < NBLK; i += 256){ a += parts[2*i]; b += parts[2*i + 1]; }
  #pragma unroll
  for (int off = 32; off; off >>= 1){
    a += __shfl_down(a, off, 64);
    b += __shfl_down(b, off, 64);
  }
  __shared__ float sa[4], sb[4];
  int wid = t >> 6, lane = t & 63;
  if (lane == 0){ sa[wid] = a; sb[wid] = b; }
  __syncthreads();
  if (t == 0){
    float A = sa[0] + sa[1] + sa[2] + sa[3];
    float B = sb[0] + sb[1] + sb[2] + sb[3];
    float mom  = A / (float)NPTS;
    float cont = B / (float)NPTS;
    out[0] = mom + 10.f * cont;
    out[1] = mom;
    out[2] = cont;
  }
}

extern "C" void kernel_launch(void* const* d_in, const int* in_sizes, int n_in,
                              void* d_out, int out_size, void* d_ws, size_t ws_size,
                              hipStream_t stream) {
  const float* pts   = (const float*)d_in[0];
  const float* times = (const float*)d_in[1];
  const float* visc  = (const float*)d_in[2];
  const float* W1    = (const float*)d_in[3];
  const float* b1    = (const float*)d_in[4];
  const float* W2    = (const float*)d_in[5];
  const float* b2    = (const float*)d_in[6];
  const float* W3    = (const float*)d_in[7];
  const float* b3    = (const float*)d_in[8];
  float* out = (float*)d_out;

  unsigned char* w2t = (unsigned char*)d_ws;
  unsigned char* w3t = (unsigned char*)d_ws + W3T_OFF;
  float* parts       = (float*)((char*)d_ws + PART_OFF);

  prep_w2t<<<128, 256, 0, stream>>>(W2, w2t);
  prep_w3t<<<16, 128, 0, stream>>>(W3, w3t);
  ns_main<<<NBLK, 512, 0, stream>>>(pts, times, visc, W1, b1, b2, b3, w2t, w3t, parts);
  ns_reduce<<<1, 256, 0, stream>>>(parts, out);
}

// Round 22
// 109.747 us; speedup vs baseline: 1.1638x; 1.1638x over previous
//
#include <hip/hip_runtime.h>

// NavierStokesLoss: fused jet-propagation (8 channels/point) through
// 4->256->256->5 tanh MLP. R22 = exact revert to R16 (109.5us, session best).
// fp8 e4m3 MFMA (absmax 0.002), 32x32x16 GEMM2 (half the MFMA issue count of
// 16x16), 4-bit XOR swizzle (0 bank conflicts), register-local recombine,
// 2-wave in-register G3 tail (optimum of narrow/wide/early-exit family),
// launch_bounds(512,6) -> 3 blocks/CU, 64-reg class, no spill.

#define NPTS 65536
#define BP   8
#define NBLK (NPTS / BP)      // 8192
#define KPADB 264             // byte stride of one W2^T row (256 fp8 + 8 pad)
#define W3T_OFF 135168
#define PART_OFF 143360

typedef float f32x4 __attribute__((ext_vector_type(4)));
typedef float f32x16 __attribute__((ext_vector_type(16)));

static __device__ __forceinline__ unsigned cvtpk_fp8(float lo, float hi){
  unsigned r = 0;
  asm("v_cvt_pk_fp8_f32 %0, %1, %2" : "+v"(r) : "v"(lo), "v"(hi));
  return r;   // bytes [0]=fp8(lo), [1]=fp8(hi)
}
static __device__ __forceinline__ float fast_tanh(float x){
  float e = __builtin_amdgcn_exp2f(x * 2.8853900817779268f);   // exp(2x)
  return 1.f - 2.f * __builtin_amdgcn_rcpf(e + 1.f);
}

// W2 (256x256 f32, [k][j]) -> w2t fp8 [j][KPADB] (transposed, padded rows)
__global__ void prep_w2t(const float* __restrict__ W2, unsigned char* __restrict__ w2t){
  int kp = blockIdx.x, j = threadIdx.x;          // 128 k-pairs
  float lo = W2[(2*kp    )*256 + j];
  float hi = W2[(2*kp + 1)*256 + j];
  *(unsigned short*)(w2t + j*KPADB + 2*kp) = (unsigned short)cvtpk_fp8(lo, hi);
}
// W3 (256x5 f32, [k][n]) -> w3t fp8 [16][256] (transposed, rows 5..15 zero)
__global__ void prep_w3t(const float* __restrict__ W3, unsigned char* __restrict__ w3t){
  int n = blockIdx.x, k2 = threadIdx.x * 2;      // 16 x 128
  float lo = (n < 5) ? W3[k2*5 + n]       : 0.f;
  float hi = (n < 5) ? W3[(k2+1)*5 + n]   : 0.f;
  *(unsigned short*)(w3t + n*256 + k2) = (unsigned short)cvtpk_fp8(lo, hi);
}

// Jet-tile row layout (64 rows x 256 fp8, 256B rows, XOR swizzle (row&15)<<3):
//   row(p,c) = (p&4)*8 + (c&4)*4 + (p&3)*4 + (c&3)
__launch_bounds__(512, 6)
__global__ void ns_main(const float* __restrict__ pts, const float* __restrict__ times,
                        const float* __restrict__ visc,
                        const float* __restrict__ W1, const float* __restrict__ b1,
                        const float* __restrict__ b2, const float* __restrict__ b3,
                        const unsigned char* __restrict__ w2t,
                        const unsigned char* __restrict__ w3t,
                        float* __restrict__ parts){
  __shared__ __align__(16) unsigned char sA[64 * 256];   // 16 KiB
  __shared__ float red[4];

  const int t   = threadIdx.x;
  const int blk = blockIdx.x;

  // ---------------- layer 1: seed the jet, write fp8 A-tile ----------------
  {
    int p  = t >> 6;            // 8 points, one wave each
    int jo = (t & 63) << 2;     // 4 consecutive j per thread
    int n  = blk * BP + p;
    float z0 = pts[n*3+0], z1 = pts[n*3+1], z2 = pts[n*3+2], z3 = times[n];
    float4 wa  = *(const float4*)(W1 + jo);
    float4 wb  = *(const float4*)(W1 + 256 + jo);
    float4 wcv = *(const float4*)(W1 + 512 + jo);
    float4 wd  = *(const float4*)(W1 + 768 + jo);
    float4 bb  = *(const float4*)(b1 + jo);
    float th[4], sg[4], m2[4];
    #pragma unroll
    for (int jj = 0; jj < 4; ++jj){
      float a = (&bb.x)[jj] + z0*(&wa.x)[jj] + z1*(&wb.x)[jj]
                            + z2*(&wcv.x)[jj] + z3*(&wd.x)[jj];
      float h = fast_tanh(a);
      th[jj] = h; sg[jj] = 1.f - h*h; m2[jj] = -2.f*h*sg[jj];
    }
    #pragma unroll
    for (int c = 0; c < 8; ++c){
      float x[4];
      #pragma unroll
      for (int jj = 0; jj < 4; ++jj){
        float w0 = (&wa.x)[jj], w1 = (&wb.x)[jj], w2 = (&wcv.x)[jj];
        float v;
        if      (c == 0) v = th[jj];
        else if (c == 1) v = sg[jj]*w0;
        else if (c == 2) v = sg[jj]*w1;
        else if (c == 3) v = sg[jj]*w2;
        else if (c == 4) v = sg[jj]*(&wd.x)[jj];
        else if (c == 5) v = m2[jj]*w0*w0;
        else if (c == 6) v = m2[jj]*w1*w1;
        else             v = m2[jj]*w2*w2;
        x[jj] = v;
      }
      int row = ((p & 4) << 3) + ((c & 4) << 2) + ((p & 3) << 2) + (c & 3);
      int off = row*256 + (jo ^ ((row & 15) << 3));
      unsigned v32 = cvtpk_fp8(x[0], x[1]) | (cvtpk_fp8(x[2], x[3]) << 16);
      *(unsigned*)(sA + off) = v32;
    }
  }
  __syncthreads();

  const int wid = t >> 6, lane = t & 63;
  const int g = lane >> 4, r16 = lane & 15;
  const int rsw = r16 << 3;          // 16x16-path swizzle (G3)
  const int l31 = lane & 31, h = lane >> 5;
  const int rsw2 = (l31 & 15) << 3;  // 32x32-path swizzle (row&15 of rows l31, 32+l31)

  // ------- GEMM2: A(64x256) @ W2 cols wid*32..+31, 32x32x16 fp8 MFMA -------
  // m-tile mt: jet rows mt*32 + l31 ; B col = wid*32 + l31 ; k-chunk = h*8
  f32x16 acc32[2];
  #pragma unroll
  for (int i = 0; i < 16; ++i){ acc32[0][i] = 0.f; acc32[1][i] = 0.f; }

  {
    const unsigned char* bp2 = w2t + (wid*32 + l31)*KPADB + h*8;
    int abase = l31*256;
    __builtin_amdgcn_s_setprio(1);
    #pragma unroll
    for (int ks = 0; ks < 16; ++ks){
      int k0 = ks * 16;
      int X  = (k0 + (h << 3)) ^ rsw2;
      long a0 = *(const long*)(sA + abase + X);
      long a1 = *(const long*)(sA + abase + 8192 + X);
      long bv = *(const long*)(bp2 + k0);
      acc32[0] = __builtin_amdgcn_mfma_f32_32x32x16_fp8_fp8(a0, bv, acc32[0], 0, 0, 0);
      acc32[1] = __builtin_amdgcn_mfma_f32_32x32x16_fp8_fp8(a1, bv, acc32[1], 0, 0, 0);
    }
    __builtin_amdgcn_s_setprio(0);
  }
  __syncthreads();   // all A-tile reads complete before in-place overwrite

  // ------- recombine (tanh jet through layer-2), register-local, fp8 writes -------
  // acc32[mt] reg r: C row-in-tile = (r&3) + 8*(r>>2) + 4*h ; col j = wid*32+l31.
  // For rr=r>>2 in {0,1}: pt = mt*4 + 2*rr + h, ch = r&3 (lo); reg r+8 = ch+4 (hi).
  {
    float b2j = b2[wid*32 + l31];
    int colj = wid*32 + l31;
    #pragma unroll
    for (int mt = 0; mt < 2; ++mt){
      #pragma unroll
      for (int rr = 0; rr < 2; ++rr){
        int pt = mt*4 + rr*2 + h;
        float gv = fast_tanh(acc32[mt][rr*4 + 0] + b2j);
        float s2 = 1.f - gv*gv;
        float t2 = -2.f * gv * s2;
        int rbase = ((pt & 4) << 3) + ((pt & 3) << 2);
        #pragma unroll
        for (int c3 = 0; c3 < 4; ++c3){
          float lo = acc32[mt][rr*4 + c3];
          float hi = acc32[mt][rr*4 + 8 + c3];
          float r_lo = (c3 == 0) ? gv : s2*lo;
          float r_hi = (c3 == 0) ? s2*hi : fmaf(t2*lo, lo, s2*hi);
          int row = rbase + c3;
          int adr = row*256 + (colj ^ ((row & 15) << 3));
          unsigned u = cvtpk_fp8(r_lo, r_hi);
          *(unsigned char*)(sA + adr)        = (unsigned char)u;
          *(unsigned char*)(sA + adr + 4096) = (unsigned char)(u >> 8);
        }
      }
    }
  }
  __syncthreads();

  // ---- GEMM3 + in-register residual tail: waves 0-1, 4 points each ----
  if (wid < 2){
    const unsigned char* w3p = w3t + r16*256 + g*8;
    int gbase = wid*8192 + r16*256;
    f32x4 a3a = (f32x4){0.f, 0.f, 0.f, 0.f};
    f32x4 a3b = (f32x4){0.f, 0.f, 0.f, 0.f};
    #pragma unroll
    for (int ks = 0; ks < 8; ++ks){
      int k0 = ks * 32;
      int X  = (k0 + (g << 3)) ^ rsw;
      long ava = *(const long*)(sA + gbase + X);
      long avb = *(const long*)(sA + gbase + 4096 + X);
      long bv3 = *(const long*)(w3p + k0);
      a3a = __builtin_amdgcn_mfma_f32_16x16x32_fp8_fp8(ava, bv3, a3a, 0, 0, 0);
      a3b = __builtin_amdgcn_mfma_f32_16x16x32_fp8_fp8(avb, bv3, a3b, 0, 0, 0);
    }
    float b3v = (r16 < 5) ? b3[r16] : 0.f;
    float o0 = a3a[0] + b3v;                   // value channel + bias
    float o1 = a3a[1], o2 = a3a[2], o3 = a3a[3];
    int sl = lane & 48;
    float u0   = __shfl(o0, sl | 0, 64);
    float u1   = __shfl(o0, sl | 1, 64);
    float u2   = __shfl(o0, sl | 2, 64);
    float rhoA = __shfl(o0, sl | 4, 64);
    float gpx  = __shfl(o1, sl | 3, 64);
    float gpy  = __shfl(o2, sl | 3, 64);
    float gpz  = __shfl(o3, sl | 3, 64);
    float c00  = __shfl(o1, sl | 0, 64);
    float c11  = __shfl(o2, sl | 1, 64);
    float c22  = __shfl(o3, sl | 2, 64);
    float rho = 1000.f * (1.f + 0.1f * fast_tanh(rhoA));
    float rr  = __builtin_amdgcn_rcpf(rho);
    float vis = visc[blk*BP + wid*4 + g];
    float lap = a3b[1] + a3b[2] + a3b[3];
    float cv  = u0*o1 + u1*o2 + u2*o3;
    float gp  = (r16 == 0) ? gpx : ((r16 == 1) ? gpy : gpz);
    float R   = a3b[0] + cv + gp*rr - vis*lap + ((r16 == 1) ? 9.81f : 0.f);
    float accM = (r16 < 3) ? R*R : 0.f;
    float accC = 0.f;
    if (r16 == 3){ float Rc = c00 + c11 + c22; accC = Rc*Rc; }
    #pragma unroll
    for (int off = 1; off < 64; off <<= 1){
      accM += __shfl_xor(accM, off, 64);
      accC += __shfl_xor(accC, off, 64);
    }
    if (lane == 0){ red[wid*2] = accM; red[wid*2+1] = accC; }
  }
  __syncthreads();
  if (t == 0){
    float2 pr; pr.x = red[0] + red[2]; pr.y = red[1] + red[3];
    *(float2*)(parts + blk*2) = pr;
  }
}

__global__ void ns_reduce(const float* __restrict__ parts, float* __restrict__ out){
  int t = threadIdx.x;
  float a = 0.f, b = 0.f;
  for (int i = t; i < NBLK; i += 256){ a += parts[2*i]; b += parts[2*i + 1]; }
  #pragma unroll
  for (int off = 32; off; off >>= 1){
    a += __shfl_down(a, off, 64);
    b += __shfl_down(b, off, 64);
  }
  __shared__ float sa[4], sb[4];
  int wid = t >> 6, lane = t & 63;
  if (lane == 0){ sa[wid] = a; sb[wid] = b; }
  __syncthreads();
  if (t == 0){
    float A = sa[0] + sa[1] + sa[2] + sa[3];
    float B = sb[0] + sb[1] + sb[2] + sb[3];
    float mom  = A / (float)NPTS;
    float cont = B / (float)NPTS;
    out[0] = mom + 10.f * cont;
    out[1] = mom;
    out[2] = cont;
  }
}

extern "C" void kernel_launch(void* const* d_in, const int* in_sizes, int n_in,
                              void* d_out, int out_size, void* d_ws, size_t ws_size,
                              hipStream_t stream) {
  const float* pts   = (const float*)d_in[0];
  const float* times = (const float*)d_in[1];
  const float* visc  = (const float*)d_in[2];
  const float* W1    = (const float*)d_in[3];
  const float* b1    = (const float*)d_in[4];
  const float* W2    = (const float*)d_in[5];
  const float* b2    = (const float*)d_in[6];
  const float* W3    = (const float*)d_in[7];
  const float* b3    = (const float*)d_in[8];
  float* out = (float*)d_out;

  unsigned char* w2t = (unsigned char*)d_ws;
  unsigned char* w3t = (unsigned char*)d_ws + W3T_OFF;
  float* parts       = (float*)((char*)d_ws + PART_OFF);

  prep_w2t<<<128, 256, 0, stream>>>(W2, w2t);
  prep_w3t<<<16, 128, 0, stream>>>(W3, w3t);
  ns_main<<<NBLK, 512, 0, stream>>>(pts, times, visc, W1, b1, b2, b3, w2t, w3t, parts);
  ns_reduce<<<1, 256, 0, stream>>>(parts, out);
}